// Round 11
// baseline (419.786 us; speedup 1.0000x reference)
//
#include <hip/hip_runtime.h>
#include <cmath>

__device__ __forceinline__ float lo16(unsigned u){ union{unsigned x; float f;} c; c.x = u << 16; return c.f; }
__device__ __forceinline__ float hi16(unsigned u){ union{unsigned x; float f;} c; c.x = u & 0xffff0000u; return c.f; }
__device__ __forceinline__ unsigned short f2bf(float f){
  union { float f; unsigned u; } c; c.f = f;
  unsigned u = c.u + 0x7FFFu + ((c.u >> 16) & 1u);
  return (unsigned short)(u >> 16);
}
__device__ __forceinline__ unsigned pack2bf(float a, float b){
  return (unsigned)f2bf(a) | ((unsigned)f2bf(b) << 16);
}
// merge factor in exp2 domain: 1 when m==M (handles -inf==-inf)
__device__ __forceinline__ float mergef2(float m, float M){ return (m == M) ? 1.f : exp2f(m - M); }

#define LOG2E 1.4426950408889634f

typedef __attribute__((ext_vector_type(8))) short bfrag;   // 8 bf16 = 4 VGPR
typedef __attribute__((ext_vector_type(4))) float ffrag;   // 4 f32 acc

// ---------------- CSR build ----------------

__global__ void deg_kernel(const int* __restrict__ dst, int* __restrict__ degi, int E){
  int e = blockIdx.x*256 + threadIdx.x;
  if (e < E) atomicAdd(&degi[dst[e]], 1);
}

__global__ void scan_p1(const int* __restrict__ degi, int* __restrict__ bsum, int N){
  __shared__ int red[256];
  int t = threadIdx.x;
  int i = blockIdx.x*256 + t;
  red[t] = (i < N) ? degi[i] : 0;
  __syncthreads();
  for (int off = 128; off > 0; off >>= 1){
    if (t < off) red[t] += red[t + off];
    __syncthreads();
  }
  if (t == 0) bsum[blockIdx.x] = red[0];
}

__global__ void scan_p2(const int* __restrict__ bsum, int* __restrict__ boff,
                        int* __restrict__ row_off, int NB, int N){
  __shared__ int s[256];
  int t = threadIdx.x;
  int v = (t < NB) ? bsum[t] : 0;
  s[t] = v;
  __syncthreads();
  for (int off = 1; off < 256; off <<= 1){
    int q = (t >= off) ? s[t - off] : 0;
    __syncthreads();
    s[t] += q;
    __syncthreads();
  }
  if (t < NB) boff[t] = s[t] - v;
  if (t == NB-1) row_off[N] = s[t];
}

// writes row_off AND cur (scatter's running cursor starts at row_off)
__global__ void scan_p3(const int* __restrict__ degi, const int* __restrict__ boff,
                        int* __restrict__ row_off, int* __restrict__ cur, int N){
  __shared__ int s[256];
  int t = threadIdx.x;
  int i = blockIdx.x*256 + t;
  int v = (i < N) ? degi[i] : 0;
  s[t] = v;
  __syncthreads();
  for (int off = 1; off < 256; off <<= 1){
    int q = (t >= off) ? s[t - off] : 0;
    __syncthreads();
    s[t] += q;
    __syncthreads();
  }
  if (i < N){
    int ro = boff[blockIdx.x] + s[t] - v;
    row_off[i] = ro;
    cur[i] = ro;
  }
}

// cur pre-initialized to row_off; also writes 4 pad entries past E (safe index 0)
__global__ void scatter_kernel(const int* __restrict__ src, const int* __restrict__ dst,
                               int* __restrict__ cur, int* __restrict__ csr_src, int E){
  int e = blockIdx.x*256 + threadIdx.x;
  if (e < E){
    int pos = atomicAdd(&cur[dst[e]], 1);
    csr_src[pos] = src[e];
  } else if (e < E + 4){
    csr_src[e] = 0;
  }
}

// ---------------- fused precision-prep: Xbf(pad) + WT1 + WT2 ----------------

__global__ void prep_all(const float* __restrict__ x,
                         const float* __restrict__ W1l, const float* __restrict__ W1r,
                         const float* __restrict__ W2l, const float* __restrict__ W2r,
                         unsigned short* __restrict__ Xbf,
                         unsigned short* __restrict__ WT1,
                         unsigned short* __restrict__ WT2, int N){
  int idx = blockIdx.x*256 + threadIdx.x;
  int n1 = N*160;              // x [N,129] -> Xbf [N,160]
  int n2 = 2*256*160;          // WT1 [512,160] from W1l/W1r [129,256]
  int n3 = 2*128*256;          // WT2 [256,256] from W2l/W2r [256,128]
  if (idx < n1){
    int n = idx / 160, k = idx - n*160;
    Xbf[idx] = (k < 129) ? f2bf(x[(size_t)n*129 + k]) : (unsigned short)0;
  } else if (idx < n1 + n2){
    int j = idx - n1;
    int c = j / 160, k = j - c*160;
    float v = 0.f;
    if (k < 129) v = (c < 256) ? W1l[(size_t)k*256 + c] : W1r[(size_t)k*256 + (c - 256)];
    WT1[j] = f2bf(v);
  } else if (idx < n1 + n2 + n3){
    int j = idx - n1 - n2;
    int c = j >> 8, k = j & 255;
    float v = (c < 128) ? W2l[(size_t)k*128 + c] : W2r[(size_t)k*128 + (c - 128)];
    WT2[j] = f2bf(v);
  }
}

// ---------------- dual MFMA bf16 GEMM, CB col-tiles of 128 per block ----------------

template<int CB>
__global__ __launch_bounds__(256) void gemm_dual(const unsigned short* __restrict__ Xbf,
                                                 const unsigned short* __restrict__ WT,
                                                 unsigned short* __restrict__ outL,
                                                 unsigned short* __restrict__ outR,
                                                 int N, int Kpad, int Mhalf){
  __shared__ __attribute__((aligned(16))) unsigned short Xs[128*40];
  __shared__ __attribute__((aligned(16))) unsigned short Ws[CB*128*40];
  int t = threadIdx.x;
  int n0 = blockIdx.x*128, c0 = blockIdx.y*(CB*128);
  int wv = t >> 6, lane = t & 63;
  int wr = wv >> 1, wc = wv & 1;
  int m16 = lane & 15, quad = lane >> 4;

  ffrag acc[CB][4][4];
  #pragma unroll
  for (int cb = 0; cb < CB; cb++)
    #pragma unroll
    for (int i = 0; i < 4; i++)
      #pragma unroll
      for (int j = 0; j < 4; j++) acc[cb][i][j] = (ffrag){0.f,0.f,0.f,0.f};

  for (int k0 = 0; k0 < Kpad; k0 += 32){
    uint4 zero = {0,0,0,0};
    #pragma unroll
    for (int it = 0; it < 2; it++){
      int idx = t + it*256;
      int r = idx >> 2, g = idx & 3;
      int n = n0 + r;
      uint4 v = (n < N) ? *(const uint4*)&Xbf[(size_t)n*Kpad + k0 + g*8] : zero;
      *(uint4*)&Xs[r*40 + g*8] = v;
    }
    #pragma unroll
    for (int it = 0; it < 2*CB; it++){
      int idx = t + it*256;
      int c = idx >> 2, g = idx & 3;
      uint4 v = *(const uint4*)&WT[(size_t)(c0 + c)*Kpad + k0 + g*8];
      *(uint4*)&Ws[c*40 + g*8] = v;
    }
    __syncthreads();
    bfrag a[4];
    #pragma unroll
    for (int i = 0; i < 4; i++)
      a[i] = *(const bfrag*)&Xs[(wr*64 + i*16 + m16)*40 + quad*8];
    #pragma unroll
    for (int cb = 0; cb < CB; cb++){
      bfrag b[4];
      #pragma unroll
      for (int j = 0; j < 4; j++)
        b[j] = *(const bfrag*)&Ws[(cb*128 + wc*64 + j*16 + m16)*40 + quad*8];
      #pragma unroll
      for (int i = 0; i < 4; i++)
        #pragma unroll
        for (int j = 0; j < 4; j++)
          acc[cb][i][j] = __builtin_amdgcn_mfma_f32_16x16x32_bf16(a[i], b[j], acc[cb][i][j], 0, 0, 0);
    }
    __syncthreads();
  }

  #pragma unroll
  for (int cb = 0; cb < CB; cb++){
    int gc0 = c0 + cb*128;
    bool isL = (gc0 < Mhalf);
    unsigned short* outp = isL ? outL : outR;
    int ccol0 = isL ? gc0 : (gc0 - Mhalf);
    #pragma unroll
    for (int i = 0; i < 4; i++){
      #pragma unroll
      for (int reg = 0; reg < 4; reg++){
        int rr = n0 + wr*64 + i*16 + quad*4 + reg;
        if (rr >= N) continue;
        #pragma unroll
        for (int j = 0; j < 4; j++){
          int cc = ccol0 + wc*64 + j*16 + m16;
          outp[(size_t)rr*Mhalf + cc] = f2bf(acc[cb][i][j][reg]);
        }
      }
    }
  }
}

// ---------------- fused GATv2 edge phase ----------------
// logit(exp2-domain) = sum[(0.6a*log2e)*t + (0.4a*log2e)*|t|],  t = xl+xr
// H=2, CH=256: wave per node, 2 edge slots x 32 lanes (16/head), 8 ch/lane. bf16 in/out.

__global__ __launch_bounds__(256) void fused_gat_wave2(
    const int* __restrict__ row_off, const int* __restrict__ csr_src,
    const unsigned short* __restrict__ xlbf, const unsigned short* __restrict__ xrbf,
    const float* __restrict__ att, const float* __restrict__ bias,
    unsigned short* __restrict__ outbf, int N)
{
  int n = blockIdx.x*4 + (threadIdx.x >> 6);
  if (n >= N) return;
  int lane = threadIdx.x & 63;
  int slot = lane >> 5;
  int sub  = lane & 31;
  int ch0  = sub*8;
  int r0 = row_off[n], r1 = row_off[n+1];
  int deg = r1 - r0;

  uint4 xru = *(const uint4*)&xrbf[(size_t)n*256 + ch0];
  float q0=lo16(xru.x), q1=hi16(xru.x), q2=lo16(xru.y), q3=hi16(xru.y);
  float q4=lo16(xru.z), q5=hi16(xru.z), q6=lo16(xru.w), q7=hi16(xru.w);
  const float4* atp = (const float4*)(att + ch0);
  float4 aa = atp[0], ab = atp[1];
  float4 p6a, p6b, p4a, p4b;
  p6a.x=0.6f*LOG2E*aa.x; p6a.y=0.6f*LOG2E*aa.y; p6a.z=0.6f*LOG2E*aa.z; p6a.w=0.6f*LOG2E*aa.w;
  p6b.x=0.6f*LOG2E*ab.x; p6b.y=0.6f*LOG2E*ab.y; p6b.z=0.6f*LOG2E*ab.z; p6b.w=0.6f*LOG2E*ab.w;
  p4a.x=0.4f*LOG2E*aa.x; p4a.y=0.4f*LOG2E*aa.y; p4a.z=0.4f*LOG2E*aa.z; p4a.w=0.4f*LOG2E*aa.w;
  p4b.x=0.4f*LOG2E*ab.x; p4b.y=0.4f*LOG2E*ab.y; p4b.z=0.4f*LOG2E*ab.z; p4b.w=0.4f*LOG2E*ab.w;

  float m = -INFINITY, l = 0.f;
  float a0=0.f,a1=0.f,a2=0.f,a3=0.f,a4=0.f,a5=0.f,a6=0.f,a7=0.f;

  const char* xlb = (const char*)xlbf;
  unsigned chb = (unsigned)ch0*2;
  int p = r0 + slot;
  unsigned off0 = ((unsigned)csr_src[p] << 9) + chb;   // pad keeps this in-bounds
  uint4 cur = *(const uint4*)(xlb + off0);
  for (; p < r1; p += 2){
    unsigned offn = ((unsigned)csr_src[p+2] << 9) + chb;
    uint4 nxt = *(const uint4*)(xlb + offn);
    float x0=lo16(cur.x), x1=hi16(cur.x), x2=lo16(cur.y), x3=hi16(cur.y);
    float x4=lo16(cur.z), x5=hi16(cur.z), x6=lo16(cur.w), x7=hi16(cur.w);
    float t0=x0+q0, t1=x1+q1, t2=x2+q2, t3=x3+q3;
    float t4=x4+q4, t5=x5+q5, t6=x6+q6, t7=x7+q7;
    float s6 = p6a.x*t0;
    s6 = fmaf(p6a.y,t1,s6); s6 = fmaf(p6a.z,t2,s6); s6 = fmaf(p6a.w,t3,s6);
    s6 = fmaf(p6b.x,t4,s6); s6 = fmaf(p6b.y,t5,s6); s6 = fmaf(p6b.z,t6,s6); s6 = fmaf(p6b.w,t7,s6);
    float s4 = p4a.x*fabsf(t0);
    s4 = fmaf(p4a.y,fabsf(t1),s4); s4 = fmaf(p4a.z,fabsf(t2),s4); s4 = fmaf(p4a.w,fabsf(t3),s4);
    s4 = fmaf(p4b.x,fabsf(t4),s4); s4 = fmaf(p4b.y,fabsf(t5),s4); s4 = fmaf(p4b.z,fabsf(t6),s4); s4 = fmaf(p4b.w,fabsf(t7),s4);
    float dot = s6 + s4;
    dot += __shfl_xor(dot, 8);
    dot += __shfl_xor(dot, 4);
    dot += __shfl_xor(dot, 2);
    dot += __shfl_xor(dot, 1);   // per-16-lane (head) logit
    if (dot <= m){
      float w_ = exp2f(dot - m);
      l += w_;
      a0 += w_*x0; a1 += w_*x1; a2 += w_*x2; a3 += w_*x3;
      a4 += w_*x4; a5 += w_*x5; a6 += w_*x6; a7 += w_*x7;
    } else {
      float sc = exp2f(m - dot);   // 0 on first edge (m=-inf)
      l = l*sc + 1.f;
      a0 = a0*sc + x0; a1 = a1*sc + x1; a2 = a2*sc + x2; a3 = a3*sc + x3;
      a4 = a4*sc + x4; a5 = a5*sc + x5; a6 = a6*sc + x6; a7 = a7*sc + x7;
      m = dot;
    }
    cur = nxt;
  }

  // slot merge
  {
    float m2 = __shfl_xor(m, 32);
    float l2 = __shfl_xor(l, 32);
    float M  = fmaxf(m, m2);
    float fa = mergef2(m, M), fb = mergef2(m2, M);
    l = l*fa + l2*fb;
    float q;
    q = __shfl_xor(a0,32); a0 = a0*fa + q*fb;
    q = __shfl_xor(a1,32); a1 = a1*fa + q*fb;
    q = __shfl_xor(a2,32); a2 = a2*fa + q*fb;
    q = __shfl_xor(a3,32); a3 = a3*fa + q*fb;
    q = __shfl_xor(a4,32); a4 = a4*fa + q*fb;
    q = __shfl_xor(a5,32); a5 = a5*fa + q*fb;
    q = __shfl_xor(a6,32); a6 = a6*fa + q*fb;
    q = __shfl_xor(a7,32); a7 = a7*fa + q*fb;
  }
  float inv = (deg > 0) ? 1.f/(l*(float)deg) : 0.f;
  const float4* bvp = (const float4*)(bias + ch0);
  float4 res0 = bvp[0], res1 = bvp[1];
  res0.x += a0*inv; res0.y += a1*inv; res0.z += a2*inv; res0.w += a3*inv;
  res1.x += a4*inv; res1.y += a5*inv; res1.z += a6*inv; res1.w += a7*inv;
  if (slot == 0){
    uint4 u;
    u.x = pack2bf(res0.x, res0.y);
    u.y = pack2bf(res0.z, res0.w);
    u.z = pack2bf(res1.x, res1.y);
    u.w = pack2bf(res1.z, res1.w);
    *(uint4*)&outbf[(size_t)n*256 + ch0] = u;
  }
}

// H=1, CH=128: wave per node, 4 edge slots x 16 lanes, 8 ch/lane.
// Fuses layer-3 projection: writes xl3[n] = h2[n].W3l, xr3[n] = h2[n].W3r (h2 never stored).

__global__ __launch_bounds__(256) void fused_gat_wave1(
    const int* __restrict__ row_off, const int* __restrict__ csr_src,
    const unsigned short* __restrict__ xlbf, const unsigned short* __restrict__ xrbf,
    const float* __restrict__ att, const float* __restrict__ bias,
    const float* __restrict__ W3l, const float* __restrict__ W3r,
    float* __restrict__ xl3, float* __restrict__ xr3, int N)
{
  int n = blockIdx.x*4 + (threadIdx.x >> 6);
  if (n >= N) return;
  int lane = threadIdx.x & 63;
  int sub  = lane & 15;
  int slot = lane >> 4;
  int ch0  = sub*8;
  int r0 = row_off[n], r1 = row_off[n+1];
  int deg = r1 - r0;

  uint4 xru = *(const uint4*)&xrbf[(size_t)n*128 + ch0];
  float q0=lo16(xru.x), q1=hi16(xru.x), q2=lo16(xru.y), q3=hi16(xru.y);
  float q4=lo16(xru.z), q5=hi16(xru.z), q6=lo16(xru.w), q7=hi16(xru.w);
  const float4* atp = (const float4*)(att + ch0);
  float4 aa = atp[0], ab = atp[1];
  float4 p6a, p6b, p4a, p4b;
  p6a.x=0.6f*LOG2E*aa.x; p6a.y=0.6f*LOG2E*aa.y; p6a.z=0.6f*LOG2E*aa.z; p6a.w=0.6f*LOG2E*aa.w;
  p6b.x=0.6f*LOG2E*ab.x; p6b.y=0.6f*LOG2E*ab.y; p6b.z=0.6f*LOG2E*ab.z; p6b.w=0.6f*LOG2E*ab.w;
  p4a.x=0.4f*LOG2E*aa.x; p4a.y=0.4f*LOG2E*aa.y; p4a.z=0.4f*LOG2E*aa.z; p4a.w=0.4f*LOG2E*aa.w;
  p4b.x=0.4f*LOG2E*ab.x; p4b.y=0.4f*LOG2E*ab.y; p4b.z=0.4f*LOG2E*ab.z; p4b.w=0.4f*LOG2E*ab.w;

  float m = -INFINITY, l = 0.f;
  float a0=0.f,a1=0.f,a2=0.f,a3=0.f,a4=0.f,a5=0.f,a6=0.f,a7=0.f;

  const char* xlb = (const char*)xlbf;
  unsigned chb = (unsigned)ch0*2;
  int p = r0 + slot;
  unsigned off0 = ((unsigned)csr_src[p] << 8) + chb;
  uint4 cur = *(const uint4*)(xlb + off0);
  for (; p < r1; p += 4){
    unsigned offn = ((unsigned)csr_src[p+4] << 8) + chb;
    uint4 nxt = *(const uint4*)(xlb + offn);
    float x0=lo16(cur.x), x1=hi16(cur.x), x2=lo16(cur.y), x3=hi16(cur.y);
    float x4=lo16(cur.z), x5=hi16(cur.z), x6=lo16(cur.w), x7=hi16(cur.w);
    float t0=x0+q0, t1=x1+q1, t2=x2+q2, t3=x3+q3;
    float t4=x4+q4, t5=x5+q5, t6=x6+q6, t7=x7+q7;
    float s6 = p6a.x*t0;
    s6 = fmaf(p6a.y,t1,s6); s6 = fmaf(p6a.z,t2,s6); s6 = fmaf(p6a.w,t3,s6);
    s6 = fmaf(p6b.x,t4,s6); s6 = fmaf(p6b.y,t5,s6); s6 = fmaf(p6b.z,t6,s6); s6 = fmaf(p6b.w,t7,s6);
    float s4 = p4a.x*fabsf(t0);
    s4 = fmaf(p4a.y,fabsf(t1),s4); s4 = fmaf(p4a.z,fabsf(t2),s4); s4 = fmaf(p4a.w,fabsf(t3),s4);
    s4 = fmaf(p4b.x,fabsf(t4),s4); s4 = fmaf(p4b.y,fabsf(t5),s4); s4 = fmaf(p4b.z,fabsf(t6),s4); s4 = fmaf(p4b.w,fabsf(t7),s4);
    float dot = s6 + s4;
    dot += __shfl_xor(dot, 8);
    dot += __shfl_xor(dot, 4);
    dot += __shfl_xor(dot, 2);
    dot += __shfl_xor(dot, 1);   // per-16-lane logit
    if (dot <= m){
      float w_ = exp2f(dot - m);
      l += w_;
      a0 += w_*x0; a1 += w_*x1; a2 += w_*x2; a3 += w_*x3;
      a4 += w_*x4; a5 += w_*x5; a6 += w_*x6; a7 += w_*x7;
    } else {
      float sc = exp2f(m - dot);
      l = l*sc + 1.f;
      a0 = a0*sc + x0; a1 = a1*sc + x1; a2 = a2*sc + x2; a3 = a3*sc + x3;
      a4 = a4*sc + x4; a5 = a5*sc + x5; a6 = a6*sc + x6; a7 = a7*sc + x7;
      m = dot;
    }
    cur = nxt;
  }

  // 2-stage slot merge -> all lanes hold merged values
  #pragma unroll
  for (int stage = 0; stage < 2; stage++){
    int d = 16 << stage;
    float m2 = __shfl_xor(m, d);
    float l2 = __shfl_xor(l, d);
    float M  = fmaxf(m, m2);
    float fa = mergef2(m, M), fb = mergef2(m2, M);
    l = l*fa + l2*fb;
    float q;
    q = __shfl_xor(a0,d); a0 = a0*fa + q*fb;
    q = __shfl_xor(a1,d); a1 = a1*fa + q*fb;
    q = __shfl_xor(a2,d); a2 = a2*fa + q*fb;
    q = __shfl_xor(a3,d); a3 = a3*fa + q*fb;
    q = __shfl_xor(a4,d); a4 = a4*fa + q*fb;
    q = __shfl_xor(a5,d); a5 = a5*fa + q*fb;
    q = __shfl_xor(a6,d); a6 = a6*fa + q*fb;
    q = __shfl_xor(a7,d); a7 = a7*fa + q*fb;
    m = M;
  }
  float inv = (deg > 0) ? 1.f/(l*(float)deg) : 0.f;
  const float4* bvp = (const float4*)(bias + ch0);
  float4 res0 = bvp[0], res1 = bvp[1];
  res0.x += a0*inv; res0.y += a1*inv; res0.z += a2*inv; res0.w += a3*inv;
  res1.x += a4*inv; res1.y += a5*inv; res1.z += a6*inv; res1.w += a7*inv;

  // layer-3 projection in-register: h2 row = res; dot with W3l/W3r
  float4 wla = *(const float4*)(W3l + ch0);
  float4 wlb = *(const float4*)(W3l + ch0 + 4);
  float4 wra = *(const float4*)(W3r + ch0);
  float4 wrb = *(const float4*)(W3r + ch0 + 4);
  float sl = res0.x*wla.x + res0.y*wla.y + res0.z*wla.z + res0.w*wla.w
           + res1.x*wlb.x + res1.y*wlb.y + res1.z*wlb.z + res1.w*wlb.w;
  float sr = res0.x*wra.x + res0.y*wra.y + res0.z*wra.z + res0.w*wra.w
           + res1.x*wrb.x + res1.y*wrb.y + res1.z*wrb.z + res1.w*wrb.w;
  sl += __shfl_xor(sl, 8); sl += __shfl_xor(sl, 4); sl += __shfl_xor(sl, 2); sl += __shfl_xor(sl, 1);
  sr += __shfl_xor(sr, 8); sr += __shfl_xor(sr, 4); sr += __shfl_xor(sr, 2); sr += __shfl_xor(sr, 1);
  if (lane == 0){ xl3[n] = sl; xr3[n] = sr; }
}

// ---------------- layer 3 aggregation (C=1), exp2 domain ----------------

__global__ __launch_bounds__(256) void aggr3_wave(
    const int* __restrict__ row_off, const int* __restrict__ csr_src,
    const float* __restrict__ xl3, const float* __restrict__ xr3,
    const float* __restrict__ a3, const float* __restrict__ b3,
    float* __restrict__ h3, int N)
{
  int n = blockIdx.x*4 + (threadIdx.x >> 6);
  if (n >= N) return;
  int lane = threadIdx.x & 63;
  int r0 = row_off[n], r1 = row_off[n+1];
  int deg = r1 - r0;
  float b = b3[0];
  if (deg == 0){ if (lane == 0) h3[n] = b; return; }
  float xrv = xr3[n];
  float aa = a3[0] * LOG2E;
  float m = -INFINITY, den = 0.f, s = 0.f;
  for (int base = r0; base < r1; base += 64){
    int p = base + lane;
    bool valid = p < r1;
    float xlv = valid ? xl3[csr_src[p]] : 0.f;
    float t = xlv + xrv;
    float v = fmaxf(t, 0.2f*t) * aa;
    if (!valid) v = -INFINITY;
    float bm = v;
    #pragma unroll
    for (int off = 32; off > 0; off >>= 1) bm = fmaxf(bm, __shfl_xor(bm, off));
    float nm = fmaxf(m, bm);
    float a = valid ? exp2f(v - nm) : 0.f;
    float bd = a, bs = a * xlv;
    #pragma unroll
    for (int off = 32; off > 0; off >>= 1){
      bd += __shfl_xor(bd, off);
      bs += __shfl_xor(bs, off);
    }
    float sc = exp2f(m - nm);
    den = den*sc + bd;
    s   = s*sc + bs;
    m = nm;
  }
  if (lane == 0) h3[n] = s/den/(float)deg + b;
}

__global__ void out_kernel(const float* __restrict__ h3, const float* __restrict__ y,
                           const int* __restrict__ tidx, float* __restrict__ out, int T){
  int i = blockIdx.x*256 + threadIdx.x;
  if (i >= T) return;
  int n = tidx[i];
  out[i] = 1.f/(1.f + __expf(-h3[n]));
  out[T + i] = y[n];
}

// ---------------- launch ----------------

extern "C" void kernel_launch(void* const* d_in, const int* in_sizes, int n_in,
                              void* d_out, int out_size, void* d_ws, size_t ws_size,
                              hipStream_t stream){
  const float* x    = (const float*)d_in[0];
  const int*   ei   = (const int*)d_in[1];
  const float* y    = (const float*)d_in[2];
  const int*   tidx = (const int*)d_in[3];
  const float* W1l  = (const float*)d_in[4];
  const float* W1r  = (const float*)d_in[5];
  const float* a1   = (const float*)d_in[6];
  const float* b1   = (const float*)d_in[7];
  const float* W2l  = (const float*)d_in[8];
  const float* W2r  = (const float*)d_in[9];
  const float* a2   = (const float*)d_in[10];
  const float* b2   = (const float*)d_in[11];
  const float* W3l  = (const float*)d_in[12];
  const float* W3r  = (const float*)d_in[13];
  const float* a3   = (const float*)d_in[14];
  const float* b3   = (const float*)d_in[15];

  int N = in_sizes[2];        // 50000 nodes
  int E = in_sizes[1] / 2;    // 800000 edges
  int T = in_sizes[3];        // 40000 train indices
  const int* src = ei;
  const int* dst = ei + E;
  int NB = (N + 255) / 256;

  char* w = (char*)d_ws;
  size_t off = 0;
  auto take = [&](size_t bytes) -> char* {
    char* p = w + off;
    off = (off + bytes + 255) & ~(size_t)255;
    return p;
  };
  int*   row_off = (int*)  take((size_t)(N+1)*4);
  int*   degi    = (int*)  take((size_t)N*4);
  int*   cur     = (int*)  take((size_t)N*4);
  int*   bsum    = (int*)  take((size_t)NB*4);
  int*   boff    = (int*)  take((size_t)NB*4);
  int*   csr_src = (int*)  take((size_t)(E+4)*4);
  unsigned short* WT1 = (unsigned short*)take((size_t)512*160*2);
  unsigned short* WT2 = (unsigned short*)take((size_t)256*256*2);
  float* A       = (float*)take((size_t)N*256*4);
  float* B       = (float*)take((size_t)N*256*4);

  // ---- CSR build ----
  hipMemsetAsync(degi, 0, (size_t)N*4, stream);
  deg_kernel<<<(E+255)/256, 256, 0, stream>>>(dst, degi, E);
  scan_p1<<<NB, 256, 0, stream>>>(degi, bsum, N);
  scan_p2<<<1, 256, 0, stream>>>(bsum, boff, row_off, NB, N);
  scan_p3<<<NB, 256, 0, stream>>>(degi, boff, row_off, cur, N);
  scatter_kernel<<<(E+4+255)/256, 256, 0, stream>>>(src, dst, cur, csr_src, E);

  // ---- buffer map (floats units) ----
  unsigned short* xl1bf = (unsigned short*)A;                   // A lower: N*256 bf16
  unsigned short* Xbf   = (unsigned short*)(A + (size_t)N*128); // A upper: N*160 bf16
  unsigned short* h1bf  = (unsigned short*)(A + (size_t)N*128); // A upper after gemm1 (Xbf dead)
  unsigned short* xr1bf = (unsigned short*)B;                   // B lower: N*256 bf16
  float* Bu   = B + (size_t)N*128;                              // B upper
  float* xl3  = Bu;
  float* xr3  = Bu + N;
  float* h3   = Bu + 2*(size_t)N;

  // ---- prep: Xbf (N x 160), WT1, WT2 ----
  int prep_total = N*160 + 2*256*160 + 2*128*256;
  prep_all<<<(prep_total+255)/256, 256, 0, stream>>>(x, W1l, W1r, W2l, W2r, Xbf, WT1, WT2, N);

  // ---- layer 1: 129 -> 256 (H=2, C=128), Kpad=160 ----
  gemm_dual<2><<<dim3((N+127)/128, 2), 256, 0, stream>>>(Xbf, WT1, xl1bf, xr1bf, N, 160, 256);
  fused_gat_wave2<<<(N+3)/4, 256, 0, stream>>>(row_off, csr_src, xl1bf, xr1bf, a1, b1, h1bf, N);

  // ---- layer 2: 256 -> 128 (H=1, C=128), Kpad=256; fuses layer-3 projection ----
  unsigned short* xl2bf = (unsigned short*)A;                   // A lower (xl1bf dead)
  unsigned short* xr2bf = (unsigned short*)B;                   // B lower (xr1bf dead)
  gemm_dual<2><<<dim3((N+127)/128, 1), 256, 0, stream>>>(h1bf, WT2, xl2bf, xr2bf, N, 256, 128);
  fused_gat_wave1<<<(N+3)/4, 256, 0, stream>>>(row_off, csr_src, xl2bf, xr2bf, a2, b2,
                                               W3l, W3r, xl3, xr3, N);

  // ---- layer 3 aggregation (C=1) ----
  aggr3_wave<<<(N+3)/4, 256, 0, stream>>>(row_off, csr_src, xl3, xr3, a3, b3, h3, N);

  // ---- output ----
  out_kernel<<<(T+255)/256, 256, 0, stream>>>(h3, y, tidx, (float*)d_out, T);
}

// Round 12
// 404.063 us; speedup vs baseline: 1.0389x; 1.0389x over previous
//
#include <hip/hip_runtime.h>
#include <cmath>

__device__ __forceinline__ float lo16(unsigned u){ union{unsigned x; float f;} c; c.x = u << 16; return c.f; }
__device__ __forceinline__ float hi16(unsigned u){ union{unsigned x; float f;} c; c.x = u & 0xffff0000u; return c.f; }
__device__ __forceinline__ float leaky(float v){ return fmaxf(v, 0.2f*v); }
__device__ __forceinline__ unsigned short f2bf(float f){
  union { float f; unsigned u; } c; c.f = f;
  unsigned u = c.u + 0x7FFFu + ((c.u >> 16) & 1u);
  return (unsigned short)(u >> 16);
}
__device__ __forceinline__ unsigned pack2bf(float a, float b){
  return (unsigned)f2bf(a) | ((unsigned)f2bf(b) << 16);
}
// merge factor in exp2 domain: 1 when m==M (handles -inf==-inf)
__device__ __forceinline__ float mergef2(float m, float M){ return (m == M) ? 1.f : exp2f(m - M); }

#define LOG2E 1.4426950408889634f

typedef __attribute__((ext_vector_type(8))) short bfrag;   // 8 bf16 = 4 VGPR
typedef __attribute__((ext_vector_type(4))) float ffrag;   // 4 f32 acc

// ---------------- CSR build ----------------

__global__ void deg_kernel(const int* __restrict__ dst, int* __restrict__ degi, int E){
  int e = blockIdx.x*256 + threadIdx.x;
  if (e < E) atomicAdd(&degi[dst[e]], 1);
}

__global__ void scan_p1(const int* __restrict__ degi, int* __restrict__ bsum, int N){
  __shared__ int red[256];
  int t = threadIdx.x;
  int i = blockIdx.x*256 + t;
  red[t] = (i < N) ? degi[i] : 0;
  __syncthreads();
  for (int off = 128; off > 0; off >>= 1){
    if (t < off) red[t] += red[t + off];
    __syncthreads();
  }
  if (t == 0) bsum[blockIdx.x] = red[0];
}

__global__ void scan_p2(const int* __restrict__ bsum, int* __restrict__ boff,
                        int* __restrict__ row_off, int NB, int N){
  __shared__ int s[256];
  int t = threadIdx.x;
  int v = (t < NB) ? bsum[t] : 0;
  s[t] = v;
  __syncthreads();
  for (int off = 1; off < 256; off <<= 1){
    int q = (t >= off) ? s[t - off] : 0;
    __syncthreads();
    s[t] += q;
    __syncthreads();
  }
  if (t < NB) boff[t] = s[t] - v;
  if (t == NB-1) row_off[N] = s[t];
}

// writes row_off AND cur (scatter's running cursor starts at row_off)
__global__ void scan_p3(const int* __restrict__ degi, const int* __restrict__ boff,
                        int* __restrict__ row_off, int* __restrict__ cur, int N){
  __shared__ int s[256];
  int t = threadIdx.x;
  int i = blockIdx.x*256 + t;
  int v = (i < N) ? degi[i] : 0;
  s[t] = v;
  __syncthreads();
  for (int off = 1; off < 256; off <<= 1){
    int q = (t >= off) ? s[t - off] : 0;
    __syncthreads();
    s[t] += q;
    __syncthreads();
  }
  if (i < N){
    int ro = boff[blockIdx.x] + s[t] - v;
    row_off[i] = ro;
    cur[i] = ro;
  }
}

// cur pre-initialized to row_off; also writes 4 pad entries past E (safe index 0)
__global__ void scatter_kernel(const int* __restrict__ src, const int* __restrict__ dst,
                               int* __restrict__ cur, int* __restrict__ csr_src, int E){
  int e = blockIdx.x*256 + threadIdx.x;
  if (e < E){
    int pos = atomicAdd(&cur[dst[e]], 1);
    csr_src[pos] = src[e];
  } else if (e < E + 4){
    csr_src[e] = 0;
  }
}

// ---------------- fused precision-prep: Xbf(pad) + WT1 + WT2 ----------------

__global__ void prep_all(const float* __restrict__ x,
                         const float* __restrict__ W1l, const float* __restrict__ W1r,
                         const float* __restrict__ W2l, const float* __restrict__ W2r,
                         unsigned short* __restrict__ Xbf,
                         unsigned short* __restrict__ WT1,
                         unsigned short* __restrict__ WT2, int N){
  int idx = blockIdx.x*256 + threadIdx.x;
  int n1 = N*160;              // x [N,129] -> Xbf [N,160]
  int n2 = 2*256*160;          // WT1 [512,160] from W1l/W1r [129,256]
  int n3 = 2*128*256;          // WT2 [256,256] from W2l/W2r [256,128]
  if (idx < n1){
    int n = idx / 160, k = idx - n*160;
    Xbf[idx] = (k < 129) ? f2bf(x[(size_t)n*129 + k]) : (unsigned short)0;
  } else if (idx < n1 + n2){
    int j = idx - n1;
    int c = j / 160, k = j - c*160;
    float v = 0.f;
    if (k < 129) v = (c < 256) ? W1l[(size_t)k*256 + c] : W1r[(size_t)k*256 + (c - 256)];
    WT1[j] = f2bf(v);
  } else if (idx < n1 + n2 + n3){
    int j = idx - n1 - n2;
    int c = j >> 8, k = j & 255;
    float v = (c < 128) ? W2l[(size_t)k*128 + c] : W2r[(size_t)k*128 + (c - 128)];
    WT2[j] = f2bf(v);
  }
}

// ---------------- dual MFMA bf16 GEMM, CB col-tiles of 128 per block ----------------

template<int CB>
__global__ __launch_bounds__(256) void gemm_dual(const unsigned short* __restrict__ Xbf,
                                                 const unsigned short* __restrict__ WT,
                                                 unsigned short* __restrict__ outL,
                                                 unsigned short* __restrict__ outR,
                                                 int N, int Kpad, int Mhalf){
  __shared__ __attribute__((aligned(16))) unsigned short Xs[128*40];
  __shared__ __attribute__((aligned(16))) unsigned short Ws[CB*128*40];
  int t = threadIdx.x;
  int n0 = blockIdx.x*128, c0 = blockIdx.y*(CB*128);
  int wv = t >> 6, lane = t & 63;
  int wr = wv >> 1, wc = wv & 1;
  int m16 = lane & 15, quad = lane >> 4;

  ffrag acc[CB][4][4];
  #pragma unroll
  for (int cb = 0; cb < CB; cb++)
    #pragma unroll
    for (int i = 0; i < 4; i++)
      #pragma unroll
      for (int j = 0; j < 4; j++) acc[cb][i][j] = (ffrag){0.f,0.f,0.f,0.f};

  for (int k0 = 0; k0 < Kpad; k0 += 32){
    uint4 zero = {0,0,0,0};
    #pragma unroll
    for (int it = 0; it < 2; it++){
      int idx = t + it*256;
      int r = idx >> 2, g = idx & 3;
      int n = n0 + r;
      uint4 v = (n < N) ? *(const uint4*)&Xbf[(size_t)n*Kpad + k0 + g*8] : zero;
      *(uint4*)&Xs[r*40 + g*8] = v;
    }
    #pragma unroll
    for (int it = 0; it < 2*CB; it++){
      int idx = t + it*256;
      int c = idx >> 2, g = idx & 3;
      uint4 v = *(const uint4*)&WT[(size_t)(c0 + c)*Kpad + k0 + g*8];
      *(uint4*)&Ws[c*40 + g*8] = v;
    }
    __syncthreads();
    bfrag a[4];
    #pragma unroll
    for (int i = 0; i < 4; i++)
      a[i] = *(const bfrag*)&Xs[(wr*64 + i*16 + m16)*40 + quad*8];
    #pragma unroll
    for (int cb = 0; cb < CB; cb++){
      bfrag b[4];
      #pragma unroll
      for (int j = 0; j < 4; j++)
        b[j] = *(const bfrag*)&Ws[(cb*128 + wc*64 + j*16 + m16)*40 + quad*8];
      #pragma unroll
      for (int i = 0; i < 4; i++)
        #pragma unroll
        for (int j = 0; j < 4; j++)
          acc[cb][i][j] = __builtin_amdgcn_mfma_f32_16x16x32_bf16(a[i], b[j], acc[cb][i][j], 0, 0, 0);
    }
    __syncthreads();
  }

  #pragma unroll
  for (int cb = 0; cb < CB; cb++){
    int gc0 = c0 + cb*128;
    bool isL = (gc0 < Mhalf);
    unsigned short* outp = isL ? outL : outR;
    int ccol0 = isL ? gc0 : (gc0 - Mhalf);
    #pragma unroll
    for (int i = 0; i < 4; i++){
      #pragma unroll
      for (int reg = 0; reg < 4; reg++){
        int rr = n0 + wr*64 + i*16 + quad*4 + reg;
        if (rr >= N) continue;
        #pragma unroll
        for (int j = 0; j < 4; j++){
          int cc = ccol0 + wc*64 + j*16 + m16;
          outp[(size_t)rr*Mhalf + cc] = f2bf(acc[cb][i][j][reg]);
        }
      }
    }
  }
}

// ---------------- fused GATv2 edge phase (round-10 structure, exp2 domain) ----------------
// att registers pre-scaled by LOG2E in place (no extra regs); logit in exp2 domain.
// H=2, CH=256: wave per node, 2 edge slots x 32 lanes (16/head), 8 ch/lane. bf16 in/out.

__global__ __launch_bounds__(256) void fused_gat_wave2(
    const int* __restrict__ row_off, const int* __restrict__ csr_src,
    const unsigned short* __restrict__ xlbf, const unsigned short* __restrict__ xrbf,
    const float* __restrict__ att, const float* __restrict__ bias,
    unsigned short* __restrict__ outbf, int N)
{
  int n = blockIdx.x*4 + (threadIdx.x >> 6);
  if (n >= N) return;
  int lane = threadIdx.x & 63;
  int slot = lane >> 5;
  int sub  = lane & 31;
  int ch0  = sub*8;
  int r0 = row_off[n], r1 = row_off[n+1];
  int deg = r1 - r0;

  uint4 xru = *(const uint4*)&xrbf[(size_t)n*256 + ch0];
  float q0=lo16(xru.x), q1=hi16(xru.x), q2=lo16(xru.y), q3=hi16(xru.y);
  float q4=lo16(xru.z), q5=hi16(xru.z), q6=lo16(xru.w), q7=hi16(xru.w);
  const float4* atp = (const float4*)(att + ch0);
  float4 ata = atp[0], atb = atp[1];
  ata.x *= LOG2E; ata.y *= LOG2E; ata.z *= LOG2E; ata.w *= LOG2E;
  atb.x *= LOG2E; atb.y *= LOG2E; atb.z *= LOG2E; atb.w *= LOG2E;

  float m = -INFINITY, l = 0.f;
  float a0=0.f,a1=0.f,a2=0.f,a3=0.f,a4=0.f,a5=0.f,a6=0.f,a7=0.f;

  const char* xlb = (const char*)xlbf;
  unsigned chb = (unsigned)ch0*2;
  int p = r0 + slot;
  unsigned off0 = ((unsigned)csr_src[p] << 9) + chb;   // pad keeps this in-bounds
  uint4 cur = *(const uint4*)(xlb + off0);
  for (; p < r1; p += 2){
    unsigned offn = ((unsigned)csr_src[p+2] << 9) + chb;
    uint4 nxt = *(const uint4*)(xlb + offn);
    float x0=lo16(cur.x), x1=hi16(cur.x), x2=lo16(cur.y), x3=hi16(cur.y);
    float x4=lo16(cur.z), x5=hi16(cur.z), x6=lo16(cur.w), x7=hi16(cur.w);
    float dot = leaky(x0+q0)*ata.x + leaky(x1+q1)*ata.y
              + leaky(x2+q2)*ata.z + leaky(x3+q3)*ata.w
              + leaky(x4+q4)*atb.x + leaky(x5+q5)*atb.y
              + leaky(x6+q6)*atb.z + leaky(x7+q7)*atb.w;
    dot += __shfl_xor(dot, 8);
    dot += __shfl_xor(dot, 4);
    dot += __shfl_xor(dot, 2);
    dot += __shfl_xor(dot, 1);   // per-16-lane (head) logit, exp2 domain
    if (dot <= m){
      float w_ = exp2f(dot - m);
      l += w_;
      a0 += w_*x0; a1 += w_*x1; a2 += w_*x2; a3 += w_*x3;
      a4 += w_*x4; a5 += w_*x5; a6 += w_*x6; a7 += w_*x7;
    } else {
      float sc = exp2f(m - dot);   // 0 on first edge (m=-inf)
      l = l*sc + 1.f;
      a0 = a0*sc + x0; a1 = a1*sc + x1; a2 = a2*sc + x2; a3 = a3*sc + x3;
      a4 = a4*sc + x4; a5 = a5*sc + x5; a6 = a6*sc + x6; a7 = a7*sc + x7;
      m = dot;
    }
    cur = nxt;
  }

  // slot merge
  {
    float m2 = __shfl_xor(m, 32);
    float l2 = __shfl_xor(l, 32);
    float M  = fmaxf(m, m2);
    float fa = mergef2(m, M), fb = mergef2(m2, M);
    l = l*fa + l2*fb;
    float q;
    q = __shfl_xor(a0,32); a0 = a0*fa + q*fb;
    q = __shfl_xor(a1,32); a1 = a1*fa + q*fb;
    q = __shfl_xor(a2,32); a2 = a2*fa + q*fb;
    q = __shfl_xor(a3,32); a3 = a3*fa + q*fb;
    q = __shfl_xor(a4,32); a4 = a4*fa + q*fb;
    q = __shfl_xor(a5,32); a5 = a5*fa + q*fb;
    q = __shfl_xor(a6,32); a6 = a6*fa + q*fb;
    q = __shfl_xor(a7,32); a7 = a7*fa + q*fb;
  }
  float inv = (deg > 0) ? 1.f/(l*(float)deg) : 0.f;
  const float4* bvp = (const float4*)(bias + ch0);
  float4 res0 = bvp[0], res1 = bvp[1];
  res0.x += a0*inv; res0.y += a1*inv; res0.z += a2*inv; res0.w += a3*inv;
  res1.x += a4*inv; res1.y += a5*inv; res1.z += a6*inv; res1.w += a7*inv;
  if (slot == 0){
    uint4 u;
    u.x = pack2bf(res0.x, res0.y);
    u.y = pack2bf(res0.z, res0.w);
    u.z = pack2bf(res1.x, res1.y);
    u.w = pack2bf(res1.z, res1.w);
    *(uint4*)&outbf[(size_t)n*256 + ch0] = u;
  }
}

// H=1, CH=128: wave per node, 4 edge slots x 16 lanes, 8 ch/lane.
// Fuses layer-3 projection: writes xl3[n] = h2[n].W3l, xr3[n] = h2[n].W3r (h2 never stored).

__global__ __launch_bounds__(256) void fused_gat_wave1(
    const int* __restrict__ row_off, const int* __restrict__ csr_src,
    const unsigned short* __restrict__ xlbf, const unsigned short* __restrict__ xrbf,
    const float* __restrict__ att, const float* __restrict__ bias,
    const float* __restrict__ W3l, const float* __restrict__ W3r,
    float* __restrict__ xl3, float* __restrict__ xr3, int N)
{
  int n = blockIdx.x*4 + (threadIdx.x >> 6);
  if (n >= N) return;
  int lane = threadIdx.x & 63;
  int sub  = lane & 15;
  int slot = lane >> 4;
  int ch0  = sub*8;
  int r0 = row_off[n], r1 = row_off[n+1];
  int deg = r1 - r0;

  uint4 xru = *(const uint4*)&xrbf[(size_t)n*128 + ch0];
  float q0=lo16(xru.x), q1=hi16(xru.x), q2=lo16(xru.y), q3=hi16(xru.y);
  float q4=lo16(xru.z), q5=hi16(xru.z), q6=lo16(xru.w), q7=hi16(xru.w);
  const float4* atp = (const float4*)(att + ch0);
  float4 ata = atp[0], atb = atp[1];
  ata.x *= LOG2E; ata.y *= LOG2E; ata.z *= LOG2E; ata.w *= LOG2E;
  atb.x *= LOG2E; atb.y *= LOG2E; atb.z *= LOG2E; atb.w *= LOG2E;

  float m = -INFINITY, l = 0.f;
  float a0=0.f,a1=0.f,a2=0.f,a3=0.f,a4=0.f,a5=0.f,a6=0.f,a7=0.f;

  const char* xlb = (const char*)xlbf;
  unsigned chb = (unsigned)ch0*2;
  int p = r0 + slot;
  unsigned off0 = ((unsigned)csr_src[p] << 8) + chb;
  uint4 cur = *(const uint4*)(xlb + off0);
  for (; p < r1; p += 4){
    unsigned offn = ((unsigned)csr_src[p+4] << 8) + chb;
    uint4 nxt = *(const uint4*)(xlb + offn);
    float x0=lo16(cur.x), x1=hi16(cur.x), x2=lo16(cur.y), x3=hi16(cur.y);
    float x4=lo16(cur.z), x5=hi16(cur.z), x6=lo16(cur.w), x7=hi16(cur.w);
    float dot = leaky(x0+q0)*ata.x + leaky(x1+q1)*ata.y
              + leaky(x2+q2)*ata.z + leaky(x3+q3)*ata.w
              + leaky(x4+q4)*atb.x + leaky(x5+q5)*atb.y
              + leaky(x6+q6)*atb.z + leaky(x7+q7)*atb.w;
    dot += __shfl_xor(dot, 8);
    dot += __shfl_xor(dot, 4);
    dot += __shfl_xor(dot, 2);
    dot += __shfl_xor(dot, 1);   // per-16-lane logit, exp2 domain
    if (dot <= m){
      float w_ = exp2f(dot - m);
      l += w_;
      a0 += w_*x0; a1 += w_*x1; a2 += w_*x2; a3 += w_*x3;
      a4 += w_*x4; a5 += w_*x5; a6 += w_*x6; a7 += w_*x7;
    } else {
      float sc = exp2f(m - dot);
      l = l*sc + 1.f;
      a0 = a0*sc + x0; a1 = a1*sc + x1; a2 = a2*sc + x2; a3 = a3*sc + x3;
      a4 = a4*sc + x4; a5 = a5*sc + x5; a6 = a6*sc + x6; a7 = a7*sc + x7;
      m = dot;
    }
    cur = nxt;
  }

  // 2-stage slot merge -> all lanes hold merged values
  #pragma unroll
  for (int stage = 0; stage < 2; stage++){
    int d = 16 << stage;
    float m2 = __shfl_xor(m, d);
    float l2 = __shfl_xor(l, d);
    float M  = fmaxf(m, m2);
    float fa = mergef2(m, M), fb = mergef2(m2, M);
    l = l*fa + l2*fb;
    float q;
    q = __shfl_xor(a0,d); a0 = a0*fa + q*fb;
    q = __shfl_xor(a1,d); a1 = a1*fa + q*fb;
    q = __shfl_xor(a2,d); a2 = a2*fa + q*fb;
    q = __shfl_xor(a3,d); a3 = a3*fa + q*fb;
    q = __shfl_xor(a4,d); a4 = a4*fa + q*fb;
    q = __shfl_xor(a5,d); a5 = a5*fa + q*fb;
    q = __shfl_xor(a6,d); a6 = a6*fa + q*fb;
    q = __shfl_xor(a7,d); a7 = a7*fa + q*fb;
    m = M;
  }
  float inv = (deg > 0) ? 1.f/(l*(float)deg) : 0.f;
  const float4* bvp = (const float4*)(bias + ch0);
  float4 res0 = bvp[0], res1 = bvp[1];
  res0.x += a0*inv; res0.y += a1*inv; res0.z += a2*inv; res0.w += a3*inv;
  res1.x += a4*inv; res1.y += a5*inv; res1.z += a6*inv; res1.w += a7*inv;

  // layer-3 projection in-register: h2 row = res; dot with W3l/W3r
  float4 wla = *(const float4*)(W3l + ch0);
  float4 wlb = *(const float4*)(W3l + ch0 + 4);
  float4 wra = *(const float4*)(W3r + ch0);
  float4 wrb = *(const float4*)(W3r + ch0 + 4);
  float sl = res0.x*wla.x + res0.y*wla.y + res0.z*wla.z + res0.w*wla.w
           + res1.x*wlb.x + res1.y*wlb.y + res1.z*wlb.z + res1.w*wlb.w;
  float sr = res0.x*wra.x + res0.y*wra.y + res0.z*wra.z + res0.w*wra.w
           + res1.x*wrb.x + res1.y*wrb.y + res1.z*wrb.z + res1.w*wrb.w;
  sl += __shfl_xor(sl, 8); sl += __shfl_xor(sl, 4); sl += __shfl_xor(sl, 2); sl += __shfl_xor(sl, 1);
  sr += __shfl_xor(sr, 8); sr += __shfl_xor(sr, 4); sr += __shfl_xor(sr, 2); sr += __shfl_xor(sr, 1);
  if (lane == 0){ xl3[n] = sl; xr3[n] = sr; }
}

// ---------------- layer 3 aggregation (C=1), exp2 domain ----------------

__global__ __launch_bounds__(256) void aggr3_wave(
    const int* __restrict__ row_off, const int* __restrict__ csr_src,
    const float* __restrict__ xl3, const float* __restrict__ xr3,
    const float* __restrict__ a3, const float* __restrict__ b3,
    float* __restrict__ h3, int N)
{
  int n = blockIdx.x*4 + (threadIdx.x >> 6);
  if (n >= N) return;
  int lane = threadIdx.x & 63;
  int r0 = row_off[n], r1 = row_off[n+1];
  int deg = r1 - r0;
  float b = b3[0];
  if (deg == 0){ if (lane == 0) h3[n] = b; return; }
  float xrv = xr3[n];
  float aa = a3[0] * LOG2E;
  float m = -INFINITY, den = 0.f, s = 0.f;
  for (int base = r0; base < r1; base += 64){
    int p = base + lane;
    bool valid = p < r1;
    float xlv = valid ? xl3[csr_src[p]] : 0.f;
    float t = xlv + xrv;
    float v = fmaxf(t, 0.2f*t) * aa;
    if (!valid) v = -INFINITY;
    float bm = v;
    #pragma unroll
    for (int off = 32; off > 0; off >>= 1) bm = fmaxf(bm, __shfl_xor(bm, off));
    float nm = fmaxf(m, bm);
    float a = valid ? exp2f(v - nm) : 0.f;
    float bd = a, bs = a * xlv;
    #pragma unroll
    for (int off = 32; off > 0; off >>= 1){
      bd += __shfl_xor(bd, off);
      bs += __shfl_xor(bs, off);
    }
    float sc = exp2f(m - nm);
    den = den*sc + bd;
    s   = s*sc + bs;
    m = nm;
  }
  if (lane == 0) h3[n] = s/den/(float)deg + b;
}

__global__ void out_kernel(const float* __restrict__ h3, const float* __restrict__ y,
                           const int* __restrict__ tidx, float* __restrict__ out, int T){
  int i = blockIdx.x*256 + threadIdx.x;
  if (i >= T) return;
  int n = tidx[i];
  out[i] = 1.f/(1.f + __expf(-h3[n]));
  out[T + i] = y[n];
}

// ---------------- launch ----------------

extern "C" void kernel_launch(void* const* d_in, const int* in_sizes, int n_in,
                              void* d_out, int out_size, void* d_ws, size_t ws_size,
                              hipStream_t stream){
  const float* x    = (const float*)d_in[0];
  const int*   ei   = (const int*)d_in[1];
  const float* y    = (const float*)d_in[2];
  const int*   tidx = (const int*)d_in[3];
  const float* W1l  = (const float*)d_in[4];
  const float* W1r  = (const float*)d_in[5];
  const float* a1   = (const float*)d_in[6];
  const float* b1   = (const float*)d_in[7];
  const float* W2l  = (const float*)d_in[8];
  const float* W2r  = (const float*)d_in[9];
  const float* a2   = (const float*)d_in[10];
  const float* b2   = (const float*)d_in[11];
  const float* W3l  = (const float*)d_in[12];
  const float* W3r  = (const float*)d_in[13];
  const float* a3   = (const float*)d_in[14];
  const float* b3   = (const float*)d_in[15];

  int N = in_sizes[2];        // 50000 nodes
  int E = in_sizes[1] / 2;    // 800000 edges
  int T = in_sizes[3];        // 40000 train indices
  const int* src = ei;
  const int* dst = ei + E;
  int NB = (N + 255) / 256;

  char* w = (char*)d_ws;
  size_t off = 0;
  auto take = [&](size_t bytes) -> char* {
    char* p = w + off;
    off = (off + bytes + 255) & ~(size_t)255;
    return p;
  };
  int*   row_off = (int*)  take((size_t)(N+1)*4);
  int*   degi    = (int*)  take((size_t)N*4);
  int*   cur     = (int*)  take((size_t)N*4);
  int*   bsum    = (int*)  take((size_t)NB*4);
  int*   boff    = (int*)  take((size_t)NB*4);
  int*   csr_src = (int*)  take((size_t)(E+4)*4);
  unsigned short* WT1 = (unsigned short*)take((size_t)512*160*2);
  unsigned short* WT2 = (unsigned short*)take((size_t)256*256*2);
  float* A       = (float*)take((size_t)N*256*4);
  float* B       = (float*)take((size_t)N*256*4);

  // ---- CSR build ----
  hipMemsetAsync(degi, 0, (size_t)N*4, stream);
  deg_kernel<<<(E+255)/256, 256, 0, stream>>>(dst, degi, E);
  scan_p1<<<NB, 256, 0, stream>>>(degi, bsum, N);
  scan_p2<<<1, 256, 0, stream>>>(bsum, boff, row_off, NB, N);
  scan_p3<<<NB, 256, 0, stream>>>(degi, boff, row_off, cur, N);
  scatter_kernel<<<(E+4+255)/256, 256, 0, stream>>>(src, dst, cur, csr_src, E);

  // ---- buffer map (floats units) ----
  unsigned short* xl1bf = (unsigned short*)A;                   // A lower: N*256 bf16
  unsigned short* Xbf   = (unsigned short*)(A + (size_t)N*128); // A upper: N*160 bf16
  unsigned short* h1bf  = (unsigned short*)(A + (size_t)N*128); // A upper after gemm1 (Xbf dead)
  unsigned short* xr1bf = (unsigned short*)B;                   // B lower: N*256 bf16
  float* Bu   = B + (size_t)N*128;                              // B upper
  float* xl3  = Bu;
  float* xr3  = Bu + N;
  float* h3   = Bu + 2*(size_t)N;

  // ---- prep: Xbf (N x 160), WT1, WT2 ----
  int prep_total = N*160 + 2*256*160 + 2*128*256;
  prep_all<<<(prep_total+255)/256, 256, 0, stream>>>(x, W1l, W1r, W2l, W2r, Xbf, WT1, WT2, N);

  // ---- layer 1: 129 -> 256 (H=2, C=128), Kpad=160 ----
  gemm_dual<2><<<dim3((N+127)/128, 2), 256, 0, stream>>>(Xbf, WT1, xl1bf, xr1bf, N, 160, 256);
  fused_gat_wave2<<<(N+3)/4, 256, 0, stream>>>(row_off, csr_src, xl1bf, xr1bf, a1, b1, h1bf, N);

  // ---- layer 2: 256 -> 128 (H=1, C=128), Kpad=256; fuses layer-3 projection ----
  unsigned short* xl2bf = (unsigned short*)A;                   // A lower (xl1bf dead)
  unsigned short* xr2bf = (unsigned short*)B;                   // B lower (xr1bf dead)
  gemm_dual<2><<<dim3((N+127)/128, 1), 256, 0, stream>>>(h1bf, WT2, xl2bf, xr2bf, N, 256, 128);
  fused_gat_wave1<<<(N+3)/4, 256, 0, stream>>>(row_off, csr_src, xl2bf, xr2bf, a2, b2,
                                               W3l, W3r, xl3, xr3, N);

  // ---- layer 3 aggregation (C=1) ----
  aggr3_wave<<<(N+3)/4, 256, 0, stream>>>(row_off, csr_src, xl3, xr3, a3, b3, h3, N);

  // ---- output ----
  out_kernel<<<(T+255)/256, 256, 0, stream>>>(h3, y, tidx, (float*)d_out, T);
}

// Round 13
// 390.145 us; speedup vs baseline: 1.0760x; 1.0357x over previous
//
#include <hip/hip_runtime.h>
#include <cmath>

__device__ __forceinline__ float lo16(unsigned u){ union{unsigned x; float f;} c; c.x = u << 16; return c.f; }
__device__ __forceinline__ float hi16(unsigned u){ union{unsigned x; float f;} c; c.x = u & 0xffff0000u; return c.f; }
__device__ __forceinline__ float leaky(float v){ return fmaxf(v, 0.2f*v); }
__device__ __forceinline__ unsigned short f2bf(float f){
  union { float f; unsigned u; } c; c.f = f;
  unsigned u = c.u + 0x7FFFu + ((c.u >> 16) & 1u);
  return (unsigned short)(u >> 16);
}
__device__ __forceinline__ unsigned pack2bf(float a, float b){
  return (unsigned)f2bf(a) | ((unsigned)f2bf(b) << 16);
}
// safe merge factor: exp(m-M), giving 1 when m==M (handles -inf==-inf)
__device__ __forceinline__ float mergef(float m, float M){ return (m == M) ? 1.f : __expf(m - M); }

#define LOG2E 1.4426950408889634f

typedef __attribute__((ext_vector_type(8))) short bfrag;   // 8 bf16 = 4 VGPR
typedef __attribute__((ext_vector_type(4))) float ffrag;   // 4 f32 acc

// ---------------- CSR build ----------------

__global__ void deg_kernel(const int* __restrict__ dst, int* __restrict__ degi, int E){
  int e = blockIdx.x*256 + threadIdx.x;
  if (e < E) atomicAdd(&degi[dst[e]], 1);
}

__global__ void scan_p1(const int* __restrict__ degi, int* __restrict__ bsum, int N){
  __shared__ int red[256];
  int t = threadIdx.x;
  int i = blockIdx.x*256 + t;
  red[t] = (i < N) ? degi[i] : 0;
  __syncthreads();
  for (int off = 128; off > 0; off >>= 1){
    if (t < off) red[t] += red[t + off];
    __syncthreads();
  }
  if (t == 0) bsum[blockIdx.x] = red[0];
}

__global__ void scan_p2(const int* __restrict__ bsum, int* __restrict__ boff,
                        int* __restrict__ row_off, int NB, int N){
  __shared__ int s[256];
  int t = threadIdx.x;
  int v = (t < NB) ? bsum[t] : 0;
  s[t] = v;
  __syncthreads();
  for (int off = 1; off < 256; off <<= 1){
    int q = (t >= off) ? s[t - off] : 0;
    __syncthreads();
    s[t] += q;
    __syncthreads();
  }
  if (t < NB) boff[t] = s[t] - v;
  if (t == NB-1) row_off[N] = s[t];
}

// writes row_off AND cur (scatter's running cursor starts at row_off)
__global__ void scan_p3(const int* __restrict__ degi, const int* __restrict__ boff,
                        int* __restrict__ row_off, int* __restrict__ cur, int N){
  __shared__ int s[256];
  int t = threadIdx.x;
  int i = blockIdx.x*256 + t;
  int v = (i < N) ? degi[i] : 0;
  s[t] = v;
  __syncthreads();
  for (int off = 1; off < 256; off <<= 1){
    int q = (t >= off) ? s[t - off] : 0;
    __syncthreads();
    s[t] += q;
    __syncthreads();
  }
  if (i < N){
    int ro = boff[blockIdx.x] + s[t] - v;
    row_off[i] = ro;
    cur[i] = ro;
  }
}

__global__ void scatter_kernel(const int* __restrict__ src, const int* __restrict__ dst,
                               int* __restrict__ cur, int* __restrict__ csr_src, int E){
  int e = blockIdx.x*256 + threadIdx.x;
  if (e < E){
    int pos = atomicAdd(&cur[dst[e]], 1);
    csr_src[pos] = src[e];
  }
}

// ---------------- fused precision-prep: Xbf(pad) + WT1 + WT2 ----------------

__global__ void prep_all(const float* __restrict__ x,
                         const float* __restrict__ W1l, const float* __restrict__ W1r,
                         const float* __restrict__ W2l, const float* __restrict__ W2r,
                         unsigned short* __restrict__ Xbf,
                         unsigned short* __restrict__ WT1,
                         unsigned short* __restrict__ WT2, int N){
  int idx = blockIdx.x*256 + threadIdx.x;
  int n1 = N*160;              // x [N,129] -> Xbf [N,160]
  int n2 = 2*256*160;          // WT1 [512,160] from W1l/W1r [129,256]
  int n3 = 2*128*256;          // WT2 [256,256] from W2l/W2r [256,128]
  if (idx < n1){
    int n = idx / 160, k = idx - n*160;
    Xbf[idx] = (k < 129) ? f2bf(x[(size_t)n*129 + k]) : (unsigned short)0;
  } else if (idx < n1 + n2){
    int j = idx - n1;
    int c = j / 160, k = j - c*160;
    float v = 0.f;
    if (k < 129) v = (c < 256) ? W1l[(size_t)k*256 + c] : W1r[(size_t)k*256 + (c - 256)];
    WT1[j] = f2bf(v);
  } else if (idx < n1 + n2 + n3){
    int j = idx - n1 - n2;
    int c = j >> 8, k = j & 255;
    float v = (c < 128) ? W2l[(size_t)k*128 + c] : W2r[(size_t)k*128 + (c - 128)];
    WT2[j] = f2bf(v);
  }
}

// ---------------- dual MFMA bf16 GEMM, CB col-tiles of 128 per block ----------------

template<int CB>
__global__ __launch_bounds__(256) void gemm_dual(const unsigned short* __restrict__ Xbf,
                                                 const unsigned short* __restrict__ WT,
                                                 unsigned short* __restrict__ outL,
                                                 unsigned short* __restrict__ outR,
                                                 int N, int Kpad, int Mhalf){
  __shared__ __attribute__((aligned(16))) unsigned short Xs[128*40];
  __shared__ __attribute__((aligned(16))) unsigned short Ws[CB*128*40];
  int t = threadIdx.x;
  int n0 = blockIdx.x*128, c0 = blockIdx.y*(CB*128);
  int wv = t >> 6, lane = t & 63;
  int wr = wv >> 1, wc = wv & 1;
  int m16 = lane & 15, quad = lane >> 4;

  ffrag acc[CB][4][4];
  #pragma unroll
  for (int cb = 0; cb < CB; cb++)
    #pragma unroll
    for (int i = 0; i < 4; i++)
      #pragma unroll
      for (int j = 0; j < 4; j++) acc[cb][i][j] = (ffrag){0.f,0.f,0.f,0.f};

  for (int k0 = 0; k0 < Kpad; k0 += 32){
    uint4 zero = {0,0,0,0};
    #pragma unroll
    for (int it = 0; it < 2; it++){
      int idx = t + it*256;
      int r = idx >> 2, g = idx & 3;
      int n = n0 + r;
      uint4 v = (n < N) ? *(const uint4*)&Xbf[(size_t)n*Kpad + k0 + g*8] : zero;
      *(uint4*)&Xs[r*40 + g*8] = v;
    }
    #pragma unroll
    for (int it = 0; it < 2*CB; it++){
      int idx = t + it*256;
      int c = idx >> 2, g = idx & 3;
      uint4 v = *(const uint4*)&WT[(size_t)(c0 + c)*Kpad + k0 + g*8];
      *(uint4*)&Ws[c*40 + g*8] = v;
    }
    __syncthreads();
    bfrag a[4];
    #pragma unroll
    for (int i = 0; i < 4; i++)
      a[i] = *(const bfrag*)&Xs[(wr*64 + i*16 + m16)*40 + quad*8];
    #pragma unroll
    for (int cb = 0; cb < CB; cb++){
      bfrag b[4];
      #pragma unroll
      for (int j = 0; j < 4; j++)
        b[j] = *(const bfrag*)&Ws[(cb*128 + wc*64 + j*16 + m16)*40 + quad*8];
      #pragma unroll
      for (int i = 0; i < 4; i++)
        #pragma unroll
        for (int j = 0; j < 4; j++)
          acc[cb][i][j] = __builtin_amdgcn_mfma_f32_16x16x32_bf16(a[i], b[j], acc[cb][i][j], 0, 0, 0);
    }
    __syncthreads();
  }

  #pragma unroll
  for (int cb = 0; cb < CB; cb++){
    int gc0 = c0 + cb*128;
    bool isL = (gc0 < Mhalf);
    unsigned short* outp = isL ? outL : outR;
    int ccol0 = isL ? gc0 : (gc0 - Mhalf);
    #pragma unroll
    for (int i = 0; i < 4; i++){
      #pragma unroll
      for (int reg = 0; reg < 4; reg++){
        int rr = n0 + wr*64 + i*16 + quad*4 + reg;
        if (rr >= N) continue;
        #pragma unroll
        for (int j = 0; j < 4; j++){
          int cc = ccol0 + wc*64 + j*16 + m16;
          outp[(size_t)rr*Mhalf + cc] = f2bf(acc[cb][i][j][reg]);
        }
      }
    }
  }
}

// ---------------- fused GATv2 edge phase (verbatim round-10 loop; 32 VGPR measured) ----------------
// H=2, CH=256: wave per node, 2 edge slots x 32 lanes (16/head), 8 ch/lane. bf16 in/out.

__global__ __launch_bounds__(256) void fused_gat_wave2(
    const int* __restrict__ row_off, const int* __restrict__ csr_src,
    const unsigned short* __restrict__ xlbf, const unsigned short* __restrict__ xrbf,
    const float* __restrict__ att, const float* __restrict__ bias,
    unsigned short* __restrict__ outbf, int N)
{
  int n = blockIdx.x*4 + (threadIdx.x >> 6);
  if (n >= N) return;
  int lane = threadIdx.x & 63;
  int slot = lane >> 5;
  int sub  = lane & 31;
  int ch0  = sub*8;
  int r0 = row_off[n], r1 = row_off[n+1];
  int deg = r1 - r0;

  uint4 xru = *(const uint4*)&xrbf[(size_t)n*256 + ch0];
  float q0=lo16(xru.x), q1=hi16(xru.x), q2=lo16(xru.y), q3=hi16(xru.y);
  float q4=lo16(xru.z), q5=hi16(xru.z), q6=lo16(xru.w), q7=hi16(xru.w);
  const float4* atp = (const float4*)(att + ch0);
  float4 ata = atp[0], atb = atp[1];

  float m = -INFINITY, l = 0.f;
  float a0=0.f,a1=0.f,a2=0.f,a3=0.f,a4=0.f,a5=0.f,a6=0.f,a7=0.f;

  if (deg > 0){
    int p = r0 + slot;
    int pc = min(p, r1-1);
    uint4 cur = *(const uint4*)&xlbf[(size_t)csr_src[pc]*256 + ch0];
    for (; p < r1; p += 2){
      int pn = min(p+2, r1-1);
      uint4 nxt = *(const uint4*)&xlbf[(size_t)csr_src[pn]*256 + ch0];
      float x0=lo16(cur.x), x1=hi16(cur.x), x2=lo16(cur.y), x3=hi16(cur.y);
      float x4=lo16(cur.z), x5=hi16(cur.z), x6=lo16(cur.w), x7=hi16(cur.w);
      float dot = leaky(x0+q0)*ata.x + leaky(x1+q1)*ata.y
                + leaky(x2+q2)*ata.z + leaky(x3+q3)*ata.w
                + leaky(x4+q4)*atb.x + leaky(x5+q5)*atb.y
                + leaky(x6+q6)*atb.z + leaky(x7+q7)*atb.w;
      dot += __shfl_xor(dot, 8);
      dot += __shfl_xor(dot, 4);
      dot += __shfl_xor(dot, 2);
      dot += __shfl_xor(dot, 1);   // per-16-lane (head) logit
      if (dot <= m){
        float w_ = __expf(dot - m);
        l += w_;
        a0 += w_*x0; a1 += w_*x1; a2 += w_*x2; a3 += w_*x3;
        a4 += w_*x4; a5 += w_*x5; a6 += w_*x6; a7 += w_*x7;
      } else {
        float sc = __expf(m - dot);   // 0 on first edge (m=-inf)
        l = l*sc + 1.f;
        a0 = a0*sc + x0; a1 = a1*sc + x1; a2 = a2*sc + x2; a3 = a3*sc + x3;
        a4 = a4*sc + x4; a5 = a5*sc + x5; a6 = a6*sc + x6; a7 = a7*sc + x7;
        m = dot;
      }
      cur = nxt;
    }
  }

  const float4* bvp = (const float4*)(bias + ch0);
  float4 res0 = bvp[0], res1 = bvp[1];
  if (deg > 0){
    float m2 = __shfl_xor(m, 32);
    float l2 = __shfl_xor(l, 32);
    float M  = fmaxf(m, m2);
    float fa = mergef(m, M), fb = mergef(m2, M);
    float L  = l*fa + l2*fb;
    float q;
    q = __shfl_xor(a0,32); a0 = a0*fa + q*fb;
    q = __shfl_xor(a1,32); a1 = a1*fa + q*fb;
    q = __shfl_xor(a2,32); a2 = a2*fa + q*fb;
    q = __shfl_xor(a3,32); a3 = a3*fa + q*fb;
    q = __shfl_xor(a4,32); a4 = a4*fa + q*fb;
    q = __shfl_xor(a5,32); a5 = a5*fa + q*fb;
    q = __shfl_xor(a6,32); a6 = a6*fa + q*fb;
    q = __shfl_xor(a7,32); a7 = a7*fa + q*fb;
    float inv = 1.f / (L * (float)deg);
    res0.x += a0*inv; res0.y += a1*inv; res0.z += a2*inv; res0.w += a3*inv;
    res1.x += a4*inv; res1.y += a5*inv; res1.z += a6*inv; res1.w += a7*inv;
  }
  if (slot == 0){
    uint4 u;
    u.x = pack2bf(res0.x, res0.y);
    u.y = pack2bf(res0.z, res0.w);
    u.z = pack2bf(res1.x, res1.y);
    u.w = pack2bf(res1.z, res1.w);
    *(uint4*)&outbf[(size_t)n*256 + ch0] = u;
  }
}

// H=1, CH=128: verbatim round-10 loop; epilogue fuses layer-3 projection
// (xl3[n] = (h2 row).W3l, xr3[n] = (h2 row).W3r; h2 never stored).

__global__ __launch_bounds__(256) void fused_gat_wave1(
    const int* __restrict__ row_off, const int* __restrict__ csr_src,
    const unsigned short* __restrict__ xlbf, const unsigned short* __restrict__ xrbf,
    const float* __restrict__ att, const float* __restrict__ bias,
    const float* __restrict__ W3l, const float* __restrict__ W3r,
    float* __restrict__ xl3, float* __restrict__ xr3, int N)
{
  int n = blockIdx.x*4 + (threadIdx.x >> 6);
  if (n >= N) return;
  int lane = threadIdx.x & 63;
  int slot = lane >> 4;
  int sub  = lane & 15;
  int ch0  = sub*8;
  int r0 = row_off[n], r1 = row_off[n+1];
  int deg = r1 - r0;

  uint4 xru = *(const uint4*)&xrbf[(size_t)n*128 + ch0];
  float q0=lo16(xru.x), q1=hi16(xru.x), q2=lo16(xru.y), q3=hi16(xru.y);
  float q4=lo16(xru.z), q5=hi16(xru.z), q6=lo16(xru.w), q7=hi16(xru.w);
  const float4* atp = (const float4*)(att + ch0);
  float4 ata = atp[0], atb = atp[1];

  float m = -INFINITY, l = 0.f;
  float a0=0.f,a1=0.f,a2=0.f,a3=0.f,a4=0.f,a5=0.f,a6=0.f,a7=0.f;

  if (deg > 0){
    int p = r0 + slot;
    int pc = min(p, r1-1);
    uint4 cur = *(const uint4*)&xlbf[(size_t)csr_src[pc]*128 + ch0];
    for (; p < r1; p += 4){
      int pn = min(p+4, r1-1);
      uint4 nxt = *(const uint4*)&xlbf[(size_t)csr_src[pn]*128 + ch0];
      float x0=lo16(cur.x), x1=hi16(cur.x), x2=lo16(cur.y), x3=hi16(cur.y);
      float x4=lo16(cur.z), x5=hi16(cur.z), x6=lo16(cur.w), x7=hi16(cur.w);
      float dot = leaky(x0+q0)*ata.x + leaky(x1+q1)*ata.y
                + leaky(x2+q2)*ata.z + leaky(x3+q3)*ata.w
                + leaky(x4+q4)*atb.x + leaky(x5+q5)*atb.y
                + leaky(x6+q6)*atb.z + leaky(x7+q7)*atb.w;
      dot += __shfl_xor(dot, 8);
      dot += __shfl_xor(dot, 4);
      dot += __shfl_xor(dot, 2);
      dot += __shfl_xor(dot, 1);   // per-16-lane logit
      if (dot <= m){
        float w_ = __expf(dot - m);
        l += w_;
        a0 += w_*x0; a1 += w_*x1; a2 += w_*x2; a3 += w_*x3;
        a4 += w_*x4; a5 += w_*x5; a6 += w_*x6; a7 += w_*x7;
      } else {
        float sc = __expf(m - dot);
        l = l*sc + 1.f;
        a0 = a0*sc + x0; a1 = a1*sc + x1; a2 = a2*sc + x2; a3 = a3*sc + x3;
        a4 = a4*sc + x4; a5 = a5*sc + x5; a6 = a6*sc + x6; a7 = a7*sc + x7;
        m = dot;
      }
      cur = nxt;
    }
  }

  if (deg > 0){
    #pragma unroll
    for (int stage = 0; stage < 2; stage++){
      int d = 16 << stage;
      float m2 = __shfl_xor(m, d);
      float l2 = __shfl_xor(l, d);
      float M  = fmaxf(m, m2);
      float fa = mergef(m, M), fb = mergef(m2, M);
      l = l*fa + l2*fb;
      float q;
      q = __shfl_xor(a0,d); a0 = a0*fa + q*fb;
      q = __shfl_xor(a1,d); a1 = a1*fa + q*fb;
      q = __shfl_xor(a2,d); a2 = a2*fa + q*fb;
      q = __shfl_xor(a3,d); a3 = a3*fa + q*fb;
      q = __shfl_xor(a4,d); a4 = a4*fa + q*fb;
      q = __shfl_xor(a5,d); a5 = a5*fa + q*fb;
      q = __shfl_xor(a6,d); a6 = a6*fa + q*fb;
      q = __shfl_xor(a7,d); a7 = a7*fa + q*fb;
      m = M;
    }
  }
  float inv = (deg > 0) ? 1.f/(l*(float)deg) : 0.f;
  const float4* bvp = (const float4*)(bias + ch0);
  float4 res0 = bvp[0], res1 = bvp[1];
  res0.x += a0*inv; res0.y += a1*inv; res0.z += a2*inv; res0.w += a3*inv;
  res1.x += a4*inv; res1.y += a5*inv; res1.z += a6*inv; res1.w += a7*inv;

  // layer-3 projection in-register: h2 row = res; dot with W3l/W3r
  float4 wla = *(const float4*)(W3l + ch0);
  float4 wlb = *(const float4*)(W3l + ch0 + 4);
  float4 wra = *(const float4*)(W3r + ch0);
  float4 wrb = *(const float4*)(W3r + ch0 + 4);
  float sl = res0.x*wla.x + res0.y*wla.y + res0.z*wla.z + res0.w*wla.w
           + res1.x*wlb.x + res1.y*wlb.y + res1.z*wlb.z + res1.w*wlb.w;
  float sr = res0.x*wra.x + res0.y*wra.y + res0.z*wra.z + res0.w*wra.w
           + res1.x*wrb.x + res1.y*wrb.y + res1.z*wrb.z + res1.w*wrb.w;
  sl += __shfl_xor(sl, 8); sl += __shfl_xor(sl, 4); sl += __shfl_xor(sl, 2); sl += __shfl_xor(sl, 1);
  sr += __shfl_xor(sr, 8); sr += __shfl_xor(sr, 4); sr += __shfl_xor(sr, 2); sr += __shfl_xor(sr, 1);
  if (lane == 0){ xl3[n] = sl; xr3[n] = sr; }
}

// ---------------- layer 3 aggregation (C=1), exp2 domain ----------------

__global__ __launch_bounds__(256) void aggr3_wave(
    const int* __restrict__ row_off, const int* __restrict__ csr_src,
    const float* __restrict__ xl3, const float* __restrict__ xr3,
    const float* __restrict__ a3, const float* __restrict__ b3,
    float* __restrict__ h3, int N)
{
  int n = blockIdx.x*4 + (threadIdx.x >> 6);
  if (n >= N) return;
  int lane = threadIdx.x & 63;
  int r0 = row_off[n], r1 = row_off[n+1];
  int deg = r1 - r0;
  float b = b3[0];
  if (deg == 0){ if (lane == 0) h3[n] = b; return; }
  float xrv = xr3[n];
  float aa = a3[0] * LOG2E;
  float m = -INFINITY, den = 0.f, s = 0.f;
  for (int base = r0; base < r1; base += 64){
    int p = base + lane;
    bool valid = p < r1;
    float xlv = valid ? xl3[csr_src[p]] : 0.f;
    float t = xlv + xrv;
    float v = fmaxf(t, 0.2f*t) * aa;
    if (!valid) v = -INFINITY;
    float bm = v;
    #pragma unroll
    for (int off = 32; off > 0; off >>= 1) bm = fmaxf(bm, __shfl_xor(bm, off));
    float nm = fmaxf(m, bm);
    float a = valid ? exp2f(v - nm) : 0.f;
    float bd = a, bs = a * xlv;
    #pragma unroll
    for (int off = 32; off > 0; off >>= 1){
      bd += __shfl_xor(bd, off);
      bs += __shfl_xor(bs, off);
    }
    float sc = exp2f(m - nm);
    den = den*sc + bd;
    s   = s*sc + bs;
    m = nm;
  }
  if (lane == 0) h3[n] = s/den/(float)deg + b;
}

__global__ void out_kernel(const float* __restrict__ h3, const float* __restrict__ y,
                           const int* __restrict__ tidx, float* __restrict__ out, int T){
  int i = blockIdx.x*256 + threadIdx.x;
  if (i >= T) return;
  int n = tidx[i];
  out[i] = 1.f/(1.f + __expf(-h3[n]));
  out[T + i] = y[n];
}

// ---------------- launch ----------------

extern "C" void kernel_launch(void* const* d_in, const int* in_sizes, int n_in,
                              void* d_out, int out_size, void* d_ws, size_t ws_size,
                              hipStream_t stream){
  const float* x    = (const float*)d_in[0];
  const int*   ei   = (const int*)d_in[1];
  const float* y    = (const float*)d_in[2];
  const int*   tidx = (const int*)d_in[3];
  const float* W1l  = (const float*)d_in[4];
  const float* W1r  = (const float*)d_in[5];
  const float* a1   = (const float*)d_in[6];
  const float* b1   = (const float*)d_in[7];
  const float* W2l  = (const float*)d_in[8];
  const float* W2r  = (const float*)d_in[9];
  const float* a2   = (const float*)d_in[10];
  const float* b2   = (const float*)d_in[11];
  const float* W3l  = (const float*)d_in[12];
  const float* W3r  = (const float*)d_in[13];
  const float* a3   = (const float*)d_in[14];
  const float* b3   = (const float*)d_in[15];

  int N = in_sizes[2];        // 50000 nodes
  int E = in_sizes[1] / 2;    // 800000 edges
  int T = in_sizes[3];        // 40000 train indices
  const int* src = ei;
  const int* dst = ei + E;
  int NB = (N + 255) / 256;

  char* w = (char*)d_ws;
  size_t off = 0;
  auto take = [&](size_t bytes) -> char* {
    char* p = w + off;
    off = (off + bytes + 255) & ~(size_t)255;
    return p;
  };
  int*   row_off = (int*)  take((size_t)(N+1)*4);
  int*   degi    = (int*)  take((size_t)N*4);
  int*   cur     = (int*)  take((size_t)N*4);
  int*   bsum    = (int*)  take((size_t)NB*4);
  int*   boff    = (int*)  take((size_t)NB*4);
  int*   csr_src = (int*)  take((size_t)E*4);
  unsigned short* WT1 = (unsigned short*)take((size_t)512*160*2);
  unsigned short* WT2 = (unsigned short*)take((size_t)256*256*2);
  float* A       = (float*)take((size_t)N*256*4);
  float* B       = (float*)take((size_t)N*256*4);

  // ---- CSR build ----
  hipMemsetAsync(degi, 0, (size_t)N*4, stream);
  deg_kernel<<<(E+255)/256, 256, 0, stream>>>(dst, degi, E);
  scan_p1<<<NB, 256, 0, stream>>>(degi, bsum, N);
  scan_p2<<<1, 256, 0, stream>>>(bsum, boff, row_off, NB, N);
  scan_p3<<<NB, 256, 0, stream>>>(degi, boff, row_off, cur, N);
  scatter_kernel<<<(E+255)/256, 256, 0, stream>>>(src, dst, cur, csr_src, E);

  // ---- buffer map (floats units) ----
  unsigned short* xl1bf = (unsigned short*)A;                   // A lower: N*256 bf16
  unsigned short* Xbf   = (unsigned short*)(A + (size_t)N*128); // A upper: N*160 bf16
  unsigned short* h1bf  = (unsigned short*)(A + (size_t)N*128); // A upper after gemm1 (Xbf dead)
  unsigned short* xr1bf = (unsigned short*)B;                   // B lower: N*256 bf16
  float* Bu   = B + (size_t)N*128;                              // B upper
  float* xl3  = Bu;
  float* xr3  = Bu + N;
  float* h3   = Bu + 2*(size_t)N;

  // ---- prep: Xbf (N x 160), WT1, WT2 ----
  int prep_total = N*160 + 2*256*160 + 2*128*256;
  prep_all<<<(prep_total+255)/256, 256, 0, stream>>>(x, W1l, W1r, W2l, W2r, Xbf, WT1, WT2, N);

  // ---- layer 1: 129 -> 256 (H=2, C=128), Kpad=160 ----
  gemm_dual<2><<<dim3((N+127)/128, 2), 256, 0, stream>>>(Xbf, WT1, xl1bf, xr1bf, N, 160, 256);
  fused_gat_wave2<<<(N+3)/4, 256, 0, stream>>>(row_off, csr_src, xl1bf, xr1bf, a1, b1, h1bf, N);

  // ---- layer 2: 256 -> 128 (H=1, C=128), Kpad=256; fuses layer-3 projection ----
  unsigned short* xl2bf = (unsigned short*)A;                   // A lower (xl1bf dead)
  unsigned short* xr2bf = (unsigned short*)B;                   // B lower (xr1bf dead)
  gemm_dual<2><<<dim3((N+127)/128, 1), 256, 0, stream>>>(h1bf, WT2, xl2bf, xr2bf, N, 256, 128);
  fused_gat_wave1<<<(N+3)/4, 256, 0, stream>>>(row_off, csr_src, xl2bf, xr2bf, a2, b2,
                                               W3l, W3r, xl3, xr3, N);

  // ---- layer 3 aggregation (C=1) ----
  aggr3_wave<<<(N+3)/4, 256, 0, stream>>>(row_off, csr_src, xl3, xr3, a3, b3, h3, N);

  // ---- output ----
  out_kernel<<<(T+255)/256, 256, 0, stream>>>(h3, y, tidx, (float*)d_out, T);
}